// Round 1
// baseline (410.907 us; speedup 1.0000x reference)
//
#include <hip/hip_runtime.h>
#include <math.h>

typedef __bf16 bf16;
typedef __attribute__((ext_vector_type(8))) __bf16 bf16x8;
typedef __attribute__((ext_vector_type(4))) float f32x4;

#define B_  2
#define S_  2048
#define H_  1024
#define NH_ 16
#define D_  64

__device__ __forceinline__ f32x4 mfma16(bf16x8 a, bf16x8 b, f32x4 c) {
    return __builtin_amdgcn_mfma_f32_16x16x32_bf16(a, b, c, 0, 0, 0);
}

// C[M,N] = A[M,K] @ W[N,K]^T.  A is fp32 (EPI=0, qkv) or bf16 (EPI=1, out-proj); W fp32.
// EPI=0: scatter epilogue -> q,k [B,NH,S,D] bf16 raw; v mixed with ve -> vt [B,NH,D,S] bf16.
// EPI=1: plain fp32 store to outF.
template <int EPI, typename AT>
__global__ __launch_bounds__(256) void gemm_bt(
    const AT* __restrict__ A, const float* __restrict__ W,
    int M, int N, int K,
    float* __restrict__ outF,
    bf16* __restrict__ qb, bf16* __restrict__ kb, bf16* __restrict__ vtb,
    const float* __restrict__ ve, const float* __restrict__ lambdas)
{
    __shared__ bf16 Al[128][40];   // +8 pad: 2-way-free b128 reads
    __shared__ bf16 Bl[128][40];
    const int m0   = blockIdx.y * 128;
    const int n0   = blockIdx.x * 128;
    const int tid  = threadIdx.x;
    const int lane = tid & 63;
    const int w    = tid >> 6;
    const int quad = lane >> 4;
    const int l16  = lane & 15;
    const int wm   = (w >> 1) * 64;   // wave's 64x64 quadrant
    const int wn   = (w & 1) * 64;
    const int sr   = tid >> 1;        // staging row 0..127
    const int sc   = (tid & 1) * 16;  // staging col 0/16

    const f32x4 Z4 = {0.f, 0.f, 0.f, 0.f};
    f32x4 acc[4][4];
#pragma unroll
    for (int i = 0; i < 4; ++i)
#pragma unroll
        for (int j = 0; j < 4; ++j) acc[i][j] = Z4;

    for (int k0 = 0; k0 < K; k0 += 32) {
        {   // stage A tile (cvt to bf16 if needed)
            const AT* src = A + (size_t)(m0 + sr) * K + k0 + sc;
            bf16x8 v0, v1;
            if constexpr (sizeof(AT) == 4) {
                f32x4 f0 = *(const f32x4*)(src);
                f32x4 f1 = *(const f32x4*)(src + 4);
                f32x4 f2 = *(const f32x4*)(src + 8);
                f32x4 f3 = *(const f32x4*)(src + 12);
#pragma unroll
                for (int j = 0; j < 4; ++j) {
                    v0[j] = (bf16)f0[j]; v0[4 + j] = (bf16)f1[j];
                    v1[j] = (bf16)f2[j]; v1[4 + j] = (bf16)f3[j];
                }
            } else {
                v0 = *(const bf16x8*)(src);
                v1 = *(const bf16x8*)(src + 8);
            }
            *(bf16x8*)&Al[sr][sc]     = v0;
            *(bf16x8*)&Al[sr][sc + 8] = v1;
        }
        {   // stage W tile (always fp32 -> bf16)
            const float* src = W + (size_t)(n0 + sr) * K + k0 + sc;
            f32x4 f0 = *(const f32x4*)(src);
            f32x4 f1 = *(const f32x4*)(src + 4);
            f32x4 f2 = *(const f32x4*)(src + 8);
            f32x4 f3 = *(const f32x4*)(src + 12);
            bf16x8 v0, v1;
#pragma unroll
            for (int j = 0; j < 4; ++j) {
                v0[j] = (bf16)f0[j]; v0[4 + j] = (bf16)f1[j];
                v1[j] = (bf16)f2[j]; v1[4 + j] = (bf16)f3[j];
            }
            *(bf16x8*)&Bl[sr][sc]     = v0;
            *(bf16x8*)&Bl[sr][sc + 8] = v1;
        }
        __syncthreads();
        bf16x8 af[4], bfg[4];
#pragma unroll
        for (int i = 0; i < 4; ++i) af[i]  = *(const bf16x8*)&Al[wm + i * 16 + l16][quad * 8];
#pragma unroll
        for (int j = 0; j < 4; ++j) bfg[j] = *(const bf16x8*)&Bl[wn + j * 16 + l16][quad * 8];
#pragma unroll
        for (int i = 0; i < 4; ++i)
#pragma unroll
            for (int j = 0; j < 4; ++j)
                acc[i][j] = mfma16(af[i], bfg[j], acc[i][j]);
        __syncthreads();
    }

    if constexpr (EPI == 1) {
#pragma unroll
        for (int i = 0; i < 4; ++i)
#pragma unroll
            for (int j = 0; j < 4; ++j)
#pragma unroll
                for (int r = 0; r < 4; ++r) {
                    int m = m0 + wm + i * 16 + quad * 4 + r;
                    int n = n0 + wn + j * 16 + l16;
                    outF[(size_t)m * N + n] = acc[i][j][r];
                }
    } else {
        const float l0 = lambdas[0], l1 = lambdas[1];
#pragma unroll
        for (int i = 0; i < 4; ++i)
#pragma unroll
            for (int j = 0; j < 4; ++j)
#pragma unroll
                for (int r = 0; r < 4; ++r) {
                    int   m   = m0 + wm + i * 16 + quad * 4 + r;
                    int   n   = n0 + wn + j * 16 + l16;
                    float val = acc[i][j][r];
                    int b = m >> 11, s = m & (S_ - 1);
                    int which = n >> 10, hn = n & (H_ - 1);
                    int h = hn >> 6, d = hn & 63;
                    int bh = b * NH_ + h;
                    if (which == 0) {
                        qb[((size_t)bh * S_ + s) * D_ + d] = (bf16)val;
                    } else if (which == 1) {
                        kb[((size_t)bh * S_ + s) * D_ + d] = (bf16)val;
                    } else {
                        float vm = l0 * val + l1 * ve[(size_t)m * H_ + hn];
                        vtb[((size_t)bh * D_ + d) * S_ + s] = (bf16)vm;
                    }
                }
    }
}

// In-place RMSNorm + RoPE over q_buf and k_buf; one wave per (b,h,s) row of 64.
__global__ __launch_bounds__(256) void qk_prep(bf16* __restrict__ qb, bf16* __restrict__ kb)
{
    const int gr   = blockIdx.x * 4 + (threadIdx.x >> 6);   // 0 .. 2*B*NH*S-1
    const int lane = threadIdx.x & 63;
    bf16* buf = (gr < B_ * NH_ * S_) ? qb : kb;
    const int rr = gr & (B_ * NH_ * S_ - 1);
    const int s  = rr & (S_ - 1);
    const size_t off = (size_t)rr * D_ + lane;

    float x  = (float)buf[off];
    float ss = x * x;
#pragma unroll
    for (int o = 32; o >= 1; o >>= 1) ss += __shfl_xor(ss, o);
    float rms = rsqrtf(ss * (1.0f / 64.0f) + 1.1920929e-07f);
    float xn  = x * rms;
    float part = __shfl_xor(xn, 32);
    int   i    = lane & 31;
    // inv_freq = 10000^(-i/32) = 2^(-i*log2(10000)/32)
    float ang = (float)s * exp2f((float)i * (-13.287712379549449f / 32.0f));
    float sn, cs;
    sincosf(ang, &sn, &cs);
    float res = xn * cs + part * ((lane < 32) ? sn : -sn);
    buf[off] = (bf16)res;
}

// Flash attention. grid = (S/64 qtiles [reversed], B*NH). Block: 4 waves x 16 queries.
__global__ __launch_bounds__(256) void attn(
    const bf16* __restrict__ Q, const bf16* __restrict__ Kg,
    const bf16* __restrict__ Vt, bf16* __restrict__ Og)
{
    __shared__ bf16 Kl[64][72];      // [key][d], +8 pad
    __shared__ bf16 Vl[64][72];      // [d][key], +8 pad
    __shared__ bf16 Pl[4][16][72];   // per-wave P tile [q][key]

    const int bh   = blockIdx.y;
    const int b    = bh >> 4;
    const int h    = bh & 15;
    const int qt   = gridDim.x - 1 - blockIdx.x;  // big blocks first
    const int tid  = threadIdx.x;
    const int lane = tid & 63;
    const int w    = tid >> 6;
    const int quad = lane >> 4;
    const int l16  = lane & 15;
    const int qbase = qt * 64 + w * 16;

    const bf16* Qp = Q  + (size_t)bh * S_ * D_;
    const bf16* Kp = Kg + (size_t)bh * S_ * D_;
    const bf16* Vp = Vt + (size_t)bh * D_ * S_;

    // Q fragments (A-layout): lane holds Q[q=qbase+l16][d=quad*8+j (+32)]
    bf16x8 qf0 = *(const bf16x8*)(Qp + (size_t)(qbase + l16) * D_ + quad * 8);
    bf16x8 qf1 = *(const bf16x8*)(Qp + (size_t)(qbase + l16) * D_ + 32 + quad * 8);

    const f32x4 Z4 = {0.f, 0.f, 0.f, 0.f};
    f32x4 of[4];
#pragma unroll
    for (int dt = 0; dt < 4; ++dt) of[dt] = Z4;
    float mrow[4], lrow[4];
#pragma unroll
    for (int r = 0; r < 4; ++r) { mrow[r] = -INFINITY; lrow[r] = 0.f; }

    const int sr  = tid >> 2;
    const int sg  = (tid & 3) * 16;
    const int nch = qt + 1;

    for (int c = 0; c < nch; ++c) {
        const int kb0 = c * 64;
        *(bf16x8*)&Kl[sr][sg]     = *(const bf16x8*)(Kp + (size_t)(kb0 + sr) * D_ + sg);
        *(bf16x8*)&Kl[sr][sg + 8] = *(const bf16x8*)(Kp + (size_t)(kb0 + sr) * D_ + sg + 8);
        *(bf16x8*)&Vl[sr][sg]     = *(const bf16x8*)(Vp + (size_t)sr * S_ + kb0 + sg);
        *(bf16x8*)&Vl[sr][sg + 8] = *(const bf16x8*)(Vp + (size_t)sr * S_ + kb0 + sg + 8);
        __syncthreads();

        // scores: 4 key-subtiles x (2 d-steps)
        f32x4 sc[4];
#pragma unroll
        for (int nt = 0; nt < 4; ++nt) {
            bf16x8 kf0 = *(const bf16x8*)&Kl[nt * 16 + l16][quad * 8];
            bf16x8 kf1 = *(const bf16x8*)&Kl[nt * 16 + l16][32 + quad * 8];
            f32x4 sacc = Z4;
            sacc = mfma16(qf0, kf0, sacc);
            sacc = mfma16(qf1, kf1, sacc);
            sc[nt] = sacc;
        }
        // scale + causal mask + row max
        float rmax[4] = {-INFINITY, -INFINITY, -INFINITY, -INFINITY};
#pragma unroll
        for (int nt = 0; nt < 4; ++nt)
#pragma unroll
            for (int r = 0; r < 4; ++r) {
                int   key = kb0 + nt * 16 + l16;
                int   qi  = qbase + quad * 4 + r;
                float v   = sc[nt][r] * 0.125f;
                v = (key <= qi) ? v : -INFINITY;
                sc[nt][r] = v;
                rmax[r]   = fmaxf(rmax[r], v);
            }
#pragma unroll
        for (int r = 0; r < 4; ++r)
#pragma unroll
            for (int o = 1; o < 16; o <<= 1) rmax[r] = fmaxf(rmax[r], __shfl_xor(rmax[r], o));

        float alpha[4], rsum[4];
#pragma unroll
        for (int r = 0; r < 4; ++r) {
            float mnew = fmaxf(mrow[r], rmax[r]);
            alpha[r] = exp2f((mrow[r] - mnew) * 1.4426950408889634f);
            mrow[r]  = mnew;
            rsum[r]  = 0.f;
        }
#pragma unroll
        for (int nt = 0; nt < 4; ++nt)
#pragma unroll
            for (int r = 0; r < 4; ++r) {
                float p = exp2f((sc[nt][r] - mrow[r]) * 1.4426950408889634f);
                sc[nt][r] = p;
                rsum[r] += p;
            }
#pragma unroll
        for (int r = 0; r < 4; ++r) {
#pragma unroll
            for (int o = 1; o < 16; o <<= 1) rsum[r] += __shfl_xor(rsum[r], o);
            lrow[r] = lrow[r] * alpha[r] + rsum[r];
#pragma unroll
            for (int dt = 0; dt < 4; ++dt) of[dt][r] *= alpha[r];
        }
        // P -> LDS (C-layout positions), read back in A-layout
#pragma unroll
        for (int nt = 0; nt < 4; ++nt)
#pragma unroll
            for (int r = 0; r < 4; ++r)
                Pl[w][quad * 4 + r][nt * 16 + l16] = (bf16)sc[nt][r];
        __syncthreads();
        bf16x8 pf0 = *(const bf16x8*)&Pl[w][l16][quad * 8];
        bf16x8 pf1 = *(const bf16x8*)&Pl[w][l16][32 + quad * 8];
#pragma unroll
        for (int dt = 0; dt < 4; ++dt) {
            bf16x8 vf0 = *(const bf16x8*)&Vl[dt * 16 + l16][quad * 8];
            bf16x8 vf1 = *(const bf16x8*)&Vl[dt * 16 + l16][32 + quad * 8];
            of[dt] = mfma16(pf0, vf0, of[dt]);
            of[dt] = mfma16(pf1, vf1, of[dt]);
        }
        __syncthreads();
    }

#pragma unroll
    for (int dt = 0; dt < 4; ++dt)
#pragma unroll
        for (int r = 0; r < 4; ++r) {
            int   qi  = qbase + quad * 4 + r;
            float val = of[dt][r] / lrow[r];
            Og[((size_t)(b * S_ + qi)) * H_ + h * D_ + dt * 16 + l16] = (bf16)val;
        }
}

extern "C" void kernel_launch(void* const* d_in, const int* in_sizes, int n_in,
                              void* d_out, int out_size, void* d_ws, size_t ws_size,
                              hipStream_t stream)
{
    const float* x       = (const float*)d_in[0];
    const float* ve      = (const float*)d_in[1];
    const float* Wqkv    = (const float*)d_in[2];
    const float* Wo      = (const float*)d_in[3];
    const float* lambdas = (const float*)d_in[4];
    float* out = (float*)d_out;

    char* ws = (char*)d_ws;
    bf16* qb  = (bf16*)(ws);                              // 8 MiB  [B,NH,S,D]
    bf16* kb  = (bf16*)(ws + (size_t)8  * 1024 * 1024);   // 8 MiB  [B,NH,S,D]
    bf16* vtb = (bf16*)(ws + (size_t)16 * 1024 * 1024);   // 8 MiB  [B,NH,D,S]
    bf16* ao  = (bf16*)(ws + (size_t)24 * 1024 * 1024);   // 8 MiB  [B,S,H]

    // 1) qkv = x @ Wqkv^T, scatter q/k raw + v mixed (transposed)
    gemm_bt<0, float><<<dim3(24, 32), 256, 0, stream>>>(
        x, Wqkv, B_ * S_, 3 * H_, H_, nullptr, qb, kb, vtb, ve, lambdas);
    // 2) RMSNorm + RoPE in place on q,k
    qk_prep<<<dim3((2 * B_ * NH_ * S_) / 4), 256, 0, stream>>>(qb, kb);
    // 3) causal flash attention -> ao [B,S,H] bf16
    attn<<<dim3(S_ / 64, B_ * NH_), 256, 0, stream>>>(qb, kb, vtb, ao);
    // 4) out = ao @ Wo^T (fp32 out)
    gemm_bt<1, bf16><<<dim3(8, 32), 256, 0, stream>>>(
        ao, Wo, B_ * S_, H_, H_, out, nullptr, nullptr, nullptr, nullptr, nullptr);
}

// Round 2
// 307.797 us; speedup vs baseline: 1.3350x; 1.3350x over previous
//
#include <hip/hip_runtime.h>
#include <math.h>

typedef __bf16 bf16;
typedef __attribute__((ext_vector_type(8))) __bf16 bf16x8;
typedef __attribute__((ext_vector_type(4))) __bf16 bf16x4;
typedef __attribute__((ext_vector_type(4))) float f32x4;

#define B_  2
#define S_  2048
#define H_  1024
#define NH_ 16
#define D_  64

__device__ __forceinline__ f32x4 mfma16(bf16x8 a, bf16x8 b, f32x4 c) {
    return __builtin_amdgcn_mfma_f32_16x16x32_bf16(a, b, c, 0, 0, 0);
}

// async global->LDS, 16B per lane; lds dest = wave-uniform base + lane*16
__device__ __forceinline__ void async16(void* lds, const void* g) {
    __builtin_amdgcn_global_load_lds(
        (const __attribute__((address_space(1))) unsigned int*)g,
        (__attribute__((address_space(3))) unsigned int*)lds, 16, 0, 0);
}

// fp32 -> bf16 bulk convert (weights), 4 elems/thread
__global__ __launch_bounds__(256) void cvt_bf16(const float* __restrict__ src,
                                                bf16* __restrict__ dst, int n4) {
    int i = blockIdx.x * 256 + threadIdx.x;
    if (i >= n4) return;
    f32x4 v = *(const f32x4*)(src + (size_t)i * 4);
    bf16x4 o;
    o[0] = (bf16)v[0]; o[1] = (bf16)v[1]; o[2] = (bf16)v[2]; o[3] = (bf16)v[3];
    *(bf16x4*)(dst + (size_t)i * 4) = o;
}

// C[M,N] = A[M,K] @ W[N,K]^T. W always bf16 (async-staged). A fp32 (cvt staging)
// or bf16 (async staging). LDS tiles use XOR chunk-swizzle: phys_chunk = c ^ (row&3).
// EPI=0: scatter q/k raw + lambda-mixed v (transposed). EPI=1: fp32 store.
template <int EPI, typename AT>
__global__ __launch_bounds__(256) void gemm_bt(
    const AT* __restrict__ A, const bf16* __restrict__ W,
    int M, int N, int K,
    float* __restrict__ outF,
    bf16* __restrict__ qb, bf16* __restrict__ kb, bf16* __restrict__ vtb,
    const float* __restrict__ ve, const float* __restrict__ lambdas)
{
    __shared__ bf16 Al[128][32];
    __shared__ bf16 Bl[128][32];
    const int m0   = blockIdx.y * 128;
    const int n0   = blockIdx.x * 128;
    const int tid  = threadIdx.x;
    const int lane = tid & 63;
    const int w    = tid >> 6;
    const int quad = lane >> 4;
    const int l16  = lane & 15;
    const int wm   = (w >> 1) * 64;
    const int wn   = (w & 1) * 64;

    const f32x4 Z4 = {0.f, 0.f, 0.f, 0.f};
    f32x4 acc[4][4];
#pragma unroll
    for (int i = 0; i < 4; ++i)
#pragma unroll
        for (int j = 0; j < 4; ++j) acc[i][j] = Z4;

    // staging geometry for async16 (1KB per instr = 16 rows of 64B)
    const int arow = lane >> 2;                       // 0..15 within group
    const int achk = (lane & 3) ^ ((lane >> 2) & 3);  // swizzled source chunk
    const int sr   = tid >> 1;                        // fp32-A path: row 0..127
    const int sc16 = (tid & 1) * 16;                  // logical col 0/16
    const int c0   = (tid & 1) * 2;                   // logical chunk pair

    for (int k0 = 0; k0 < K; k0 += 32) {
        // ---- B tile: async, wave w covers rows w*32 .. w*32+31 ----
        {
            const bf16* gB = W + (size_t)(n0 + w * 32 + arow) * K + k0 + achk * 8;
            async16(&Bl[w * 32][0], gB);
            async16(&Bl[w * 32 + 16][0], gB + (size_t)16 * K);
        }
        // ---- A tile ----
        if constexpr (sizeof(AT) == 2) {
            const bf16* gA = (const bf16*)A + (size_t)(m0 + w * 32 + arow) * K + k0 + achk * 8;
            async16(&Al[w * 32][0], gA);
            async16(&Al[w * 32 + 16][0], gA + (size_t)16 * K);
        } else {
            const float* src = (const float*)A + (size_t)(m0 + sr) * K + k0 + sc16;
            f32x4 f0 = *(const f32x4*)(src);
            f32x4 f1 = *(const f32x4*)(src + 4);
            f32x4 f2 = *(const f32x4*)(src + 8);
            f32x4 f3 = *(const f32x4*)(src + 12);
            bf16x8 v0, v1;
#pragma unroll
            for (int j = 0; j < 4; ++j) {
                v0[j] = (bf16)f0[j]; v0[4 + j] = (bf16)f1[j];
                v1[j] = (bf16)f2[j]; v1[4 + j] = (bf16)f3[j];
            }
            *(bf16x8*)&Al[sr][((c0 + 0) ^ (sr & 3)) * 8] = v0;
            *(bf16x8*)&Al[sr][((c0 + 1) ^ (sr & 3)) * 8] = v1;
        }
        __syncthreads();
        bf16x8 af[4], bfg[4];
#pragma unroll
        for (int i = 0; i < 4; ++i)
            af[i]  = *(const bf16x8*)&Al[wm + i * 16 + l16][(quad ^ (l16 & 3)) * 8];
#pragma unroll
        for (int j = 0; j < 4; ++j)
            bfg[j] = *(const bf16x8*)&Bl[wn + j * 16 + l16][(quad ^ (l16 & 3)) * 8];
#pragma unroll
        for (int i = 0; i < 4; ++i)
#pragma unroll
            for (int j = 0; j < 4; ++j)
                acc[i][j] = mfma16(af[i], bfg[j], acc[i][j]);
        __syncthreads();
    }

    if constexpr (EPI == 1) {
#pragma unroll
        for (int i = 0; i < 4; ++i)
#pragma unroll
            for (int j = 0; j < 4; ++j)
#pragma unroll
                for (int r = 0; r < 4; ++r) {
                    int m = m0 + wm + i * 16 + quad * 4 + r;
                    int n = n0 + wn + j * 16 + l16;
                    outF[(size_t)m * N + n] = acc[i][j][r];
                }
    } else {
        const float l0 = lambdas[0], l1 = lambdas[1];
#pragma unroll
        for (int i = 0; i < 4; ++i)
#pragma unroll
            for (int j = 0; j < 4; ++j)
#pragma unroll
                for (int r = 0; r < 4; ++r) {
                    int   m   = m0 + wm + i * 16 + quad * 4 + r;
                    int   n   = n0 + wn + j * 16 + l16;
                    float val = acc[i][j][r];
                    int b = m >> 11, s = m & (S_ - 1);
                    int which = n >> 10, hn = n & (H_ - 1);
                    int h = hn >> 6, d = hn & 63;
                    int bh = b * NH_ + h;
                    if (which == 0) {
                        qb[((size_t)bh * S_ + s) * D_ + d] = (bf16)val;
                    } else if (which == 1) {
                        kb[((size_t)bh * S_ + s) * D_ + d] = (bf16)val;
                    } else {
                        float vm = l0 * val + l1 * ve[(size_t)m * H_ + hn];
                        vtb[((size_t)bh * D_ + d) * S_ + s] = (bf16)vm;
                    }
                }
    }
}

// In-place RMSNorm + RoPE on q,k; one wave per 64-elem head row.
__global__ __launch_bounds__(256) void qk_prep(bf16* __restrict__ qb, bf16* __restrict__ kb)
{
    const int gr   = blockIdx.x * 4 + (threadIdx.x >> 6);
    const int lane = threadIdx.x & 63;
    bf16* buf = (gr < B_ * NH_ * S_) ? qb : kb;
    const int rr = gr & (B_ * NH_ * S_ - 1);
    const int s  = rr & (S_ - 1);
    const size_t off = (size_t)rr * D_ + lane;

    float x  = (float)buf[off];
    float ss = x * x;
#pragma unroll
    for (int o = 32; o >= 1; o >>= 1) ss += __shfl_xor(ss, o);
    float rms = rsqrtf(ss * (1.0f / 64.0f) + 1.1920929e-07f);
    float xn  = x * rms;
    float part = __shfl_xor(xn, 32);
    int   i    = lane & 31;
    float ang = (float)s * exp2f((float)i * (-13.287712379549449f / 32.0f));
    float sn, cs;
    sincosf(ang, &sn, &cs);
    float res = xn * cs + part * ((lane < 32) ? sn : -sn);
    buf[off] = (bf16)res;
}

// Flash attention, balanced pairing: block handles q-tiles {pair, 31-pair} (33 chunks).
// QK with A=K,B=Q -> S^T in C-layout (key-contiguous per lane). Static max = 8
// (RMSNorm bounds |score*0.125| <= 8): no running max / alpha. K/V/P in LDS with
// XOR chunk-swizzle (phys_chunk = c ^ (row&7)); K/V staged via global_load_lds.
__global__ __launch_bounds__(256) void attn(
    const bf16* __restrict__ Q, const bf16* __restrict__ Kg,
    const bf16* __restrict__ Vt, bf16* __restrict__ Og)
{
    __shared__ bf16 Kl[64][64];
    __shared__ bf16 Vl[64][64];
    __shared__ bf16 Pl[4][16][64];

    const int bh   = blockIdx.y;
    const int b    = bh >> 4;
    const int h    = bh & 15;
    const int tid  = threadIdx.x;
    const int lane = tid & 63;
    const int w    = tid >> 6;
    const int quad = lane >> 4;
    const int l16  = lane & 15;
    const int l7   = l16 & 7;

    const bf16* Qp = Q  + (size_t)bh * S_ * D_;
    const bf16* Kp = Kg + (size_t)bh * S_ * D_;
    const bf16* Vp = Vt + (size_t)bh * D_ * S_;

    const int srow = lane >> 3;               // 0..7 within 8-row group
    const int schk = (lane & 7) ^ (lane >> 3); // swizzled source chunk
    const f32x4 Z4 = {0.f, 0.f, 0.f, 0.f};
    const float C1 = 0.18033688011112042f;    // 0.125*log2(e)
    const float C2 = -11.541560327111707f;    // -8*log2(e)

    for (int half = 0; half < 2; ++half) {
        const int qt    = half ? (31 - blockIdx.x) : blockIdx.x;
        const int qbase = qt * 64 + w * 16;
        const int qi    = qbase + l16;

        bf16x8 qf0 = *(const bf16x8*)(Qp + (size_t)(qbase + l16) * D_ + quad * 8);
        bf16x8 qf1 = *(const bf16x8*)(Qp + (size_t)(qbase + l16) * D_ + 32 + quad * 8);

        f32x4 of[4];
#pragma unroll
        for (int dt = 0; dt < 4; ++dt) of[dt] = Z4;
        float lsum = 0.f;

        const int nch = qt + 1;
        for (int c = 0; c < nch; ++c) {
            const int kb0 = c * 64;
            {   // stage K,V: wave w covers rows w*16 .. w*16+15 of each
                const bf16* gK = Kp + (size_t)(kb0 + w * 16 + srow) * D_ + schk * 8;
                async16(&Kl[w * 16][0], gK);
                async16(&Kl[w * 16 + 8][0], gK + (size_t)8 * D_);
                const bf16* gV = Vp + (size_t)(w * 16 + srow) * S_ + kb0 + schk * 8;
                async16(&Vl[w * 16][0], gV);
                async16(&Vl[w * 16 + 8][0], gV + (size_t)8 * S_);
            }
            __syncthreads();

            float ps = 0.f;
#pragma unroll
            for (int nt = 0; nt < 4; ++nt) {
                bf16x8 kf0 = *(const bf16x8*)&Kl[nt * 16 + l16][(quad ^ l7) * 8];
                bf16x8 kf1 = *(const bf16x8*)&Kl[nt * 16 + l16][((quad + 4) ^ l7) * 8];
                f32x4 sacc = Z4;
                sacc = mfma16(kf0, qf0, sacc);
                sacc = mfma16(kf1, qf1, sacc);
                bf16x4 pk;
#pragma unroll
                for (int r = 0; r < 4; ++r) {
                    int   key = kb0 + nt * 16 + quad * 4 + r;
                    float e   = fmaf(sacc[r], C1, C2);
                    float p   = (key <= qi) ? exp2f(e) : 0.f;
                    ps += p;
                    pk[r] = (bf16)p;
                }
                *(bf16x4*)&Pl[w][l16][((nt * 2 + (quad >> 1)) ^ l7) * 8 + (quad & 1) * 4] = pk;
            }
            ps += __shfl_xor(ps, 16);
            ps += __shfl_xor(ps, 32);
            lsum += ps;

            bf16x8 pf0 = *(const bf16x8*)&Pl[w][l16][(quad ^ l7) * 8];
            bf16x8 pf1 = *(const bf16x8*)&Pl[w][l16][((quad + 4) ^ l7) * 8];
#pragma unroll
            for (int dt = 0; dt < 4; ++dt) {
                bf16x8 vf0 = *(const bf16x8*)&Vl[dt * 16 + l16][(quad ^ l7) * 8];
                bf16x8 vf1 = *(const bf16x8*)&Vl[dt * 16 + l16][((quad + 4) ^ l7) * 8];
                of[dt] = mfma16(pf0, vf0, of[dt]);
                of[dt] = mfma16(pf1, vf1, of[dt]);
            }
            __syncthreads();
        }

#pragma unroll
        for (int r = 0; r < 4; ++r) {
            float ld = __shfl(lsum, quad * 4 + r);
            float rl = 1.0f / ld;
            int   qq = qbase + quad * 4 + r;
#pragma unroll
            for (int dt = 0; dt < 4; ++dt)
                Og[((size_t)(b * S_ + qq)) * H_ + h * D_ + dt * 16 + l16] =
                    (bf16)(of[dt][r] * rl);
        }
    }
}

extern "C" void kernel_launch(void* const* d_in, const int* in_sizes, int n_in,
                              void* d_out, int out_size, void* d_ws, size_t ws_size,
                              hipStream_t stream)
{
    const float* x       = (const float*)d_in[0];
    const float* ve      = (const float*)d_in[1];
    const float* Wqkv    = (const float*)d_in[2];
    const float* Wo      = (const float*)d_in[3];
    const float* lambdas = (const float*)d_in[4];
    float* out = (float*)d_out;

    // ws layout (32 MiB peak, phase-aliased):
    //   [0,6M)   wqb  (live: cvt..gemm1)      -> [0,8M)  ao (live: attn..gemm2)
    //   [8M,16M) qb   (live: gemm1..attn)     -> [8M,10M) wob (live: cvt_wo..gemm2)
    //   [16M,24M) kb  (live: gemm1..attn)
    //   [24M,32M) vtb (live: gemm1..attn)
    char* ws = (char*)d_ws;
    const size_t MB = 1024 * 1024;
    bf16* wqb = (bf16*)(ws);
    bf16* ao  = (bf16*)(ws);
    bf16* qb  = (bf16*)(ws + 8 * MB);
    bf16* wob = (bf16*)(ws + 8 * MB);
    bf16* kb  = (bf16*)(ws + 16 * MB);
    bf16* vtb = (bf16*)(ws + 24 * MB);

    // 1) convert W_qkv to bf16
    cvt_bf16<<<3072, 256, 0, stream>>>(Wqkv, wqb, (3 * H_ * H_) / 4);
    // 2) qkv = x @ Wqkv^T, scatter q/k raw + v mixed (transposed)
    gemm_bt<0, float><<<dim3(24, 32), 256, 0, stream>>>(
        x, wqb, B_ * S_, 3 * H_, H_, nullptr, qb, kb, vtb, ve, lambdas);
    // 3) RMSNorm + RoPE in place on q,k
    qk_prep<<<dim3((2 * B_ * NH_ * S_) / 4), 256, 0, stream>>>(qb, kb);
    // 4) balanced causal flash attention -> ao
    attn<<<dim3(16, B_ * NH_), 256, 0, stream>>>(qb, kb, vtb, ao);
    // 5) convert W_o to bf16 (into retired qb space)
    cvt_bf16<<<1024, 256, 0, stream>>>(Wo, wob, (H_ * H_) / 4);
    // 6) out = ao @ Wo^T (fp32)
    gemm_bt<1, bf16><<<dim3(8, 32), 256, 0, stream>>>(
        ao, wob, B_ * S_, H_, H_, out, nullptr, nullptr, nullptr, nullptr, nullptr);
}

// Round 3
// 244.101 us; speedup vs baseline: 1.6834x; 1.2609x over previous
//
#include <hip/hip_runtime.h>
#include <math.h>

typedef __bf16 bf16;
typedef __attribute__((ext_vector_type(8))) __bf16 bf16x8;
typedef __attribute__((ext_vector_type(4))) __bf16 bf16x4;
typedef __attribute__((ext_vector_type(4))) float f32x4;

#define B_  2
#define S_  2048
#define H_  1024
#define NH_ 16
#define D_  64

__device__ __forceinline__ f32x4 mfma16(bf16x8 a, bf16x8 b, f32x4 c) {
    return __builtin_amdgcn_mfma_f32_16x16x32_bf16(a, b, c, 0, 0, 0);
}

// async global->LDS, 16B per lane; lds dest = wave-uniform base + lane*16
__device__ __forceinline__ void async16(void* lds, const void* g) {
    __builtin_amdgcn_global_load_lds(
        (const __attribute__((address_space(1))) unsigned int*)g,
        (__attribute__((address_space(3))) unsigned int*)lds, 16, 0, 0);
}

// fp32 -> bf16 bulk convert, 4 elems/thread
__global__ __launch_bounds__(256) void cvt_bf16(const float* __restrict__ src,
                                                bf16* __restrict__ dst, int n4) {
    int i = blockIdx.x * 256 + threadIdx.x;
    if (i >= n4) return;
    f32x4 v = *(const f32x4*)(src + (size_t)i * 4);
    bf16x4 o;
    o[0] = (bf16)v[0]; o[1] = (bf16)v[1]; o[2] = (bf16)v[2]; o[3] = (bf16)v[3];
    *(bf16x4*)(dst + (size_t)i * 4) = o;
}

// C[M,N] = A[M,K] @ W[N,K]^T, both bf16, both tiles via global_load_lds (m97
// structure). XOR chunk-swizzle: physical chunk = logical ^ (row&3).
// EPI=0 (qkv): per-wave 64-col range = one (q|k|v, head); fused RMSNorm+RoPE
//   epilogue for q/k, lambda-mix + transpose store for v.
// EPI=1: plain fp32 store.
template <int EPI>
__global__ __launch_bounds__(256) void gemm_bt(
    const bf16* __restrict__ A, const bf16* __restrict__ W,
    int M, int N, int K,
    float* __restrict__ outF,
    bf16* __restrict__ qb, bf16* __restrict__ kb, bf16* __restrict__ vtb,
    const float* __restrict__ ve, const float* __restrict__ lambdas)
{
    __shared__ bf16 Al[128][32];
    __shared__ bf16 Bl[128][32];
    const int m0   = blockIdx.y * 128;
    const int n0   = blockIdx.x * 128;
    const int tid  = threadIdx.x;
    const int lane = tid & 63;
    const int w    = tid >> 6;
    const int quad = lane >> 4;
    const int l16  = lane & 15;
    const int wm   = (w >> 1) * 64;
    const int wn   = (w & 1) * 64;
    const int arow = lane >> 2;                       // 0..15 within 16-row group
    const int achk = (lane & 3) ^ ((lane >> 2) & 3);  // swizzled source chunk

    const f32x4 Z4 = {0.f, 0.f, 0.f, 0.f};
    f32x4 acc[4][4];
#pragma unroll
    for (int i = 0; i < 4; ++i)
#pragma unroll
        for (int j = 0; j < 4; ++j) acc[i][j] = Z4;

    for (int k0 = 0; k0 < K; k0 += 32) {
        const bf16* gB = W + (size_t)(n0 + w * 32 + arow) * K + k0 + achk * 8;
        async16(&Bl[w * 32][0], gB);
        async16(&Bl[w * 32 + 16][0], gB + (size_t)16 * K);
        const bf16* gA = A + (size_t)(m0 + w * 32 + arow) * K + k0 + achk * 8;
        async16(&Al[w * 32][0], gA);
        async16(&Al[w * 32 + 16][0], gA + (size_t)16 * K);
        __syncthreads();
        bf16x8 af[4], bfg[4];
#pragma unroll
        for (int i = 0; i < 4; ++i)
            af[i]  = *(const bf16x8*)&Al[wm + i * 16 + l16][(quad ^ (l16 & 3)) * 8];
#pragma unroll
        for (int j = 0; j < 4; ++j)
            bfg[j] = *(const bf16x8*)&Bl[wn + j * 16 + l16][(quad ^ (l16 & 3)) * 8];
#pragma unroll
        for (int i = 0; i < 4; ++i)
#pragma unroll
            for (int j = 0; j < 4; ++j)
                acc[i][j] = mfma16(af[i], bfg[j], acc[i][j]);
        __syncthreads();
    }

    if constexpr (EPI == 1) {
#pragma unroll
        for (int i = 0; i < 4; ++i)
#pragma unroll
            for (int j = 0; j < 4; ++j)
#pragma unroll
                for (int r = 0; r < 4; ++r) {
                    int m = m0 + wm + i * 16 + quad * 4 + r;
                    int n = n0 + wn + j * 16 + l16;
                    outF[(size_t)m * N + n] = acc[i][j][r];
                }
    } else {
        const int nbase = n0 + wn;              // wave-uniform
        const int which = nbase >> 10;          // 0=q 1=k 2=v
        const int h     = (nbase & (H_ - 1)) >> 6;
        if (which < 2) {
            bf16* dst = which ? kb : qb;
            const float KF = -13.287712379549449f / 32.0f;  // -log2(10000)/32
            const float fl = exp2f((float)l16 * KF);
            const float fh = exp2f((float)(l16 + 16) * KF);
#pragma unroll
            for (int i = 0; i < 4; ++i) {
                float ss[4];
#pragma unroll
                for (int r = 0; r < 4; ++r)
                    ss[r] = acc[i][0][r] * acc[i][0][r] + acc[i][1][r] * acc[i][1][r]
                          + acc[i][2][r] * acc[i][2][r] + acc[i][3][r] * acc[i][3][r];
#pragma unroll
                for (int r = 0; r < 4; ++r) {
                    ss[r] += __shfl_xor(ss[r], 1);
                    ss[r] += __shfl_xor(ss[r], 2);
                    ss[r] += __shfl_xor(ss[r], 4);
                    ss[r] += __shfl_xor(ss[r], 8);
                }
#pragma unroll
                for (int r = 0; r < 4; ++r) {
                    int   m   = m0 + wm + i * 16 + quad * 4 + r;
                    int   bb  = m >> 11, s = m & (S_ - 1);
                    float rms = rsqrtf(ss[r] * (1.0f / 64.0f) + 1.1920929e-07f);
                    float x0 = acc[i][0][r] * rms, x1 = acc[i][1][r] * rms;
                    float x2 = acc[i][2][r] * rms, x3 = acc[i][3][r] * rms;
                    float sl, cl, sh, ch;
                    sincosf((float)s * fl, &sl, &cl);
                    sincosf((float)s * fh, &sh, &ch);
                    bf16* bp = dst + ((size_t)(bb * NH_ + h) * S_ + s) * D_;
                    bp[l16]      = (bf16)(x0 * cl + x2 * sl);
                    bp[16 + l16] = (bf16)(x1 * ch + x3 * sh);
                    bp[32 + l16] = (bf16)(x2 * cl - x0 * sl);
                    bp[48 + l16] = (bf16)(x3 * ch - x1 * sh);
                }
            }
        } else {
            const float l0 = lambdas[0], l1 = lambdas[1];
#pragma unroll
            for (int i = 0; i < 4; ++i)
#pragma unroll
                for (int j = 0; j < 4; ++j)
#pragma unroll
                    for (int r = 0; r < 4; ++r) {
                        int   m  = m0 + wm + i * 16 + quad * 4 + r;
                        int   bb = m >> 11, s = m & (S_ - 1);
                        int   d  = j * 16 + l16;
                        float vm = l0 * acc[i][j][r]
                                 + l1 * ve[(size_t)m * H_ + h * 64 + d];
                        vtb[((size_t)(bb * NH_ + h) * D_ + d) * S_ + s] = (bf16)vm;
                    }
        }
    }
}

// Flash attention, balanced pairing {bx, 31-bx} (33 chunks/block), static max=8,
// swapped-operand QK (scores transposed, key-contiguous), double-buffered K/V
// staging via global_load_lds: one barrier per chunk, prefetch c+1 issued before
// compute of c so the barrier's vmcnt drain lands after a full compute phase.
__global__ __launch_bounds__(256) void attn(
    const bf16* __restrict__ Q, const bf16* __restrict__ Kg,
    const bf16* __restrict__ Vt, bf16* __restrict__ Og)
{
    __shared__ bf16 Kl[2][64][64];
    __shared__ bf16 Vl[2][64][64];
    __shared__ bf16 Pl[4][16][64];

    const int bh   = blockIdx.y;
    const int b    = bh >> 4;
    const int h    = bh & 15;
    const int tid  = threadIdx.x;
    const int lane = tid & 63;
    const int w    = tid >> 6;
    const int quad = lane >> 4;
    const int l16  = lane & 15;
    const int l7   = l16 & 7;

    const bf16* Qp = Q  + (size_t)bh * S_ * D_;
    const bf16* Kp = Kg + (size_t)bh * S_ * D_;
    const bf16* Vp = Vt + (size_t)bh * D_ * S_;

    const int srow = lane >> 3;                // 0..7 within 8-row group
    const int schk = (lane & 7) ^ (lane >> 3); // swizzled source chunk
    const f32x4 Z4 = {0.f, 0.f, 0.f, 0.f};
    const float C1 = 0.18033688011112042f;     // 0.125*log2(e)
    const float C2 = -11.541560327111707f;     // -8*log2(e)

    auto stage = [&](int p, int kb0) {
        const bf16* gK = Kp + (size_t)(kb0 + w * 16 + srow) * D_ + schk * 8;
        async16(&Kl[p][w * 16][0], gK);
        async16(&Kl[p][w * 16 + 8][0], gK + (size_t)8 * D_);
        const bf16* gV = Vp + (size_t)(w * 16 + srow) * S_ + kb0 + schk * 8;
        async16(&Vl[p][w * 16][0], gV);
        async16(&Vl[p][w * 16 + 8][0], gV + (size_t)8 * S_);
    };

    for (int half = 0; half < 2; ++half) {
        const int qt    = half ? (31 - blockIdx.x) : blockIdx.x;
        const int qbase = qt * 64 + w * 16;
        const int qi    = qbase + l16;

        bf16x8 qf0 = *(const bf16x8*)(Qp + (size_t)(qbase + l16) * D_ + quad * 8);
        bf16x8 qf1 = *(const bf16x8*)(Qp + (size_t)(qbase + l16) * D_ + 32 + quad * 8);

        f32x4 of[4];
#pragma unroll
        for (int dt = 0; dt < 4; ++dt) of[dt] = Z4;
        float lsum = 0.f;

        const int nch = qt + 1;
        __syncthreads();           // prev half's compute done before restaging buf0
        stage(0, 0);
        for (int c = 0; c < nch; ++c) {
            const int p   = c & 1;
            const int kb0 = c * 64;
            __syncthreads();       // buf[p] staged (barrier drains vmcnt)
            if (c + 1 < nch) stage(p ^ 1, kb0 + 64);

            float ps = 0.f;
#pragma unroll
            for (int nt = 0; nt < 4; ++nt) {
                bf16x8 kf0 = *(const bf16x8*)&Kl[p][nt * 16 + l16][(quad ^ l7) * 8];
                bf16x8 kf1 = *(const bf16x8*)&Kl[p][nt * 16 + l16][((quad + 4) ^ l7) * 8];
                f32x4 sacc = Z4;
                sacc = mfma16(kf0, qf0, sacc);
                sacc = mfma16(kf1, qf1, sacc);
                bf16x4 pk;
#pragma unroll
                for (int r = 0; r < 4; ++r) {
                    int   key = kb0 + nt * 16 + quad * 4 + r;
                    float e   = fmaf(sacc[r], C1, C2);
                    float pv  = (key <= qi) ? exp2f(e) : 0.f;
                    ps += pv;
                    pk[r] = (bf16)pv;
                }
                *(bf16x4*)&Pl[w][l16][((nt * 2 + (quad >> 1)) ^ l7) * 8 + (quad & 1) * 4] = pk;
            }
            ps += __shfl_xor(ps, 16);
            ps += __shfl_xor(ps, 32);
            lsum += ps;

            bf16x8 pf0 = *(const bf16x8*)&Pl[w][l16][(quad ^ l7) * 8];
            bf16x8 pf1 = *(const bf16x8*)&Pl[w][l16][((quad + 4) ^ l7) * 8];
#pragma unroll
            for (int dt = 0; dt < 4; ++dt) {
                bf16x8 vf0 = *(const bf16x8*)&Vl[p][dt * 16 + l16][(quad ^ l7) * 8];
                bf16x8 vf1 = *(const bf16x8*)&Vl[p][dt * 16 + l16][((quad + 4) ^ l7) * 8];
                of[dt] = mfma16(pf0, vf0, of[dt]);
                of[dt] = mfma16(pf1, vf1, of[dt]);
            }
        }

#pragma unroll
        for (int r = 0; r < 4; ++r) {
            float ld = __shfl(lsum, quad * 4 + r);
            float rl = 1.0f / ld;
            int   qq = qbase + quad * 4 + r;
#pragma unroll
            for (int dt = 0; dt < 4; ++dt)
                Og[((size_t)(b * S_ + qq)) * H_ + h * D_ + dt * 16 + l16] =
                    (bf16)(of[dt][r] * rl);
        }
    }
}

extern "C" void kernel_launch(void* const* d_in, const int* in_sizes, int n_in,
                              void* d_out, int out_size, void* d_ws, size_t ws_size,
                              hipStream_t stream)
{
    const float* x       = (const float*)d_in[0];
    const float* ve      = (const float*)d_in[1];
    const float* Wqkv    = (const float*)d_in[2];
    const float* Wo      = (const float*)d_in[3];
    const float* lambdas = (const float*)d_in[4];
    float* out = (float*)d_out;

    // d_out (16 MiB) doubles as early-phase scratch: xb [0,8M), wqb [8M,14M).
    // Both die after gemm1; gemm2 overwrites d_out with the final output.
    // ws (32 MiB): qb [0,8M), kb [8,16M), vtb [16,24M), ao [24,32M);
    // wob reuses [0,2M) after attn retires qb.
    char* od = (char*)d_out;
    char* ws = (char*)d_ws;
    const size_t MB = 1024 * 1024;
    bf16* xb  = (bf16*)(od);
    bf16* wqb = (bf16*)(od + 8 * MB);
    bf16* qb  = (bf16*)(ws);
    bf16* kb  = (bf16*)(ws + 8 * MB);
    bf16* vtb = (bf16*)(ws + 16 * MB);
    bf16* ao  = (bf16*)(ws + 24 * MB);
    bf16* wob = (bf16*)(ws);

    // 1) pre-convert x and W_qkv to bf16 (into d_out scratch)
    cvt_bf16<<<4096, 256, 0, stream>>>(x, xb, (B_ * S_ * H_) / 4);
    cvt_bf16<<<3072, 256, 0, stream>>>(Wqkv, wqb, (3 * H_ * H_) / 4);
    // 2) qkv GEMM, fused RMSNorm+RoPE (q,k) + lambda-mix transpose (v)
    gemm_bt<0><<<dim3(24, 32), 256, 0, stream>>>(
        xb, wqb, B_ * S_, 3 * H_, H_, nullptr, qb, kb, vtb, ve, lambdas);
    // 3) balanced causal flash attention -> ao
    attn<<<dim3(16, B_ * NH_), 256, 0, stream>>>(qb, kb, vtb, ao);
    // 4) convert W_o (into retired qb space)
    cvt_bf16<<<1024, 256, 0, stream>>>(Wo, wob, (H_ * H_) / 4);
    // 5) out = ao @ Wo^T (fp32, overwrites d_out)
    gemm_bt<1><<<dim3(8, 32), 256, 0, stream>>>(
        ao, wob, B_ * S_, H_, H_, out, nullptr, nullptr, nullptr, nullptr, nullptr);
}